// Round 1
// baseline (162.296 us; speedup 1.0000x reference)
//
#include <hip/hip_runtime.h>
#include <hip/hip_bf16.h>

#define NB 8
#define NT 2048
#define NC 1024
#define NH 64

typedef __attribute__((ext_vector_type(8))) short bf16x8;
typedef __attribute__((ext_vector_type(4))) short bf16x4;
typedef __attribute__((ext_vector_type(4))) float f32x4;

__device__ __forceinline__ unsigned short f2bf(float f) {
  __hip_bfloat16 h = __float2bfloat16(f);
  return __builtin_bit_cast(unsigned short, h);
}

__device__ __forceinline__ f32x4 mfma32(bf16x8 a, bf16x8 b, f32x4 c) {
  return __builtin_amdgcn_mfma_f32_16x16x32_bf16(a, b, c, 0, 0, 0);
}

#if __has_builtin(__builtin_amdgcn_mfma_f32_16x16x16bf16_1k)
__device__ __forceinline__ f32x4 mfma16(bf16x4 a, bf16x4 b, f32x4 c) {
  return __builtin_amdgcn_mfma_f32_16x16x16bf16_1k(a, b, c, 0, 0, 0);
}
#else
__device__ __forceinline__ f32x4 mfma16(bf16x4 a, bf16x4 b, f32x4 c) {
  asm volatile("v_mfma_f32_16x16x16_bf16 %0, %1, %2, %0\n\ts_nop 7"
               : "+v"(c) : "v"(a), "v"(b));
  return c;
}
#endif

// ---------------------------------------------------------------------------
// Kernel 0: weight transpose+convert. W[1024][64] f32 -> Wt[64][1024] bf16.
// Folds softmax scale * log2(e) into Wq so attention can use exp2 directly.
// grid = 48 (3 weights x 16 k-tiles), block = 256.
// ---------------------------------------------------------------------------
__global__ __launch_bounds__(256) void wt_kernel(const float* __restrict__ Wq,
                                                 const float* __restrict__ Wk,
                                                 const float* __restrict__ Wv,
                                                 unsigned short* __restrict__ Wt) {
  __shared__ float lds[64][65];
  int wi = blockIdx.x >> 4, kt = blockIdx.x & 15;
  const float* W = (wi == 0) ? Wq : ((wi == 1) ? Wk : Wv);
  // 0.125 (H^-0.5) * 1.4426950408889634 (log2 e)
  float scale = (wi == 0) ? 0.18033688011112043f : 1.0f;
  int tid = threadIdx.x;
#pragma unroll
  for (int i = 0; i < 16; ++i) {
    int idx = tid + i * 256;
    lds[idx >> 6][idx & 63] = W[(size_t)(kt * 64 + (idx >> 6)) * NH + (idx & 63)] * scale;
  }
  __syncthreads();
#pragma unroll
  for (int i = 0; i < 16; ++i) {
    int idx = tid + i * 256;
    int n = idx >> 6, kk = idx & 63;
    Wt[(size_t)(wi * 64 + n) * NC + kt * 64 + kk] = f2bf(lds[kk][n]);
  }
}

// ---------------------------------------------------------------------------
// Kernel 1: fused QKV projection. x[16384][1024] f32 @ Wt^T -> q,k [B*T][64]
// bf16 and v transposed to [B][64][T] bf16. grid = 256 blocks x 256 thr
// (4 waves x 16 rows each), mfma 16x16x32 bf16, 12 n-fragments (q|k|v).
// ---------------------------------------------------------------------------
__global__ __launch_bounds__(256) void proj_kernel(const float* __restrict__ x,
                                                   const unsigned short* __restrict__ Wt,
                                                   unsigned short* __restrict__ qo,
                                                   unsigned short* __restrict__ ko,
                                                   unsigned short* __restrict__ vo) {
  int tid = threadIdx.x;
  int lane = tid & 63, w = tid >> 6;
  int ln = lane & 15, g = lane >> 4;
  int row0 = blockIdx.x * 64;
  int rw = row0 + w * 16 + ln;                     // A-frag row (token)
  const float* xp = x + (size_t)rw * NC + g * 8;   // k = c0 + g*8 + j
  const unsigned short* wp[12];
#pragma unroll
  for (int f = 0; f < 12; ++f) {
    int wi = f >> 2, n = (f & 3) * 16 + ln;
    wp[f] = Wt + (size_t)(wi * 64 + n) * NC + g * 8;
  }
  f32x4 acc[12];
#pragma unroll
  for (int f = 0; f < 12; ++f) acc[f] = (f32x4){0.f, 0.f, 0.f, 0.f};

#pragma unroll
  for (int c0 = 0; c0 < NC; c0 += 32) {
    float4 a0 = *(const float4*)(xp + c0);
    float4 a1 = *(const float4*)(xp + c0 + 4);
    bf16x8 af;
    af[0] = (short)f2bf(a0.x); af[1] = (short)f2bf(a0.y);
    af[2] = (short)f2bf(a0.z); af[3] = (short)f2bf(a0.w);
    af[4] = (short)f2bf(a1.x); af[5] = (short)f2bf(a1.y);
    af[6] = (short)f2bf(a1.z); af[7] = (short)f2bf(a1.w);
#pragma unroll
    for (int f = 0; f < 12; ++f) {
      bf16x8 bfr = *(const bf16x8*)(wp[f] + c0);
      acc[f] = mfma32(af, bfr, acc[f]);
    }
  }

  // q, k: D layout row=(g*4+r), col=ln -> 32B segments, acceptable.
#pragma unroll
  for (int f = 0; f < 8; ++f) {
    unsigned short* dst = (f < 4) ? qo : ko;
    int hh = (f & 3) * 16 + ln;
#pragma unroll
    for (int r = 0; r < 4; ++r) {
      int row = row0 + w * 16 + g * 4 + r;
      dst[(size_t)row * NH + hh] = f2bf(acc[f][r]);
    }
  }

  // v -> LDS transpose -> vT[b][h][t] coalesced 16B stores
  __shared__ unsigned short vlds[64][68];
#pragma unroll
  for (int f = 8; f < 12; ++f)
#pragma unroll
    for (int r = 0; r < 4; ++r)
      vlds[(f - 8) * 16 + ln][w * 16 + g * 4 + r] = f2bf(acc[f][r]);
  __syncthreads();
  int b = row0 / NT, t0b = row0 % NT;
  int hh = tid >> 2, ts = (tid & 3) * 16;
  unsigned short tmp[16];
#pragma unroll
  for (int i = 0; i < 16; ++i) tmp[i] = vlds[hh][ts + i];
  bf16x8* dst = (bf16x8*)(vo + (size_t)(b * NH + hh) * NT + t0b + ts);
  dst[0] = *(bf16x8*)(tmp);
  dst[1] = *(bf16x8*)(tmp + 8);
}

// ---------------------------------------------------------------------------
// Kernel 2: causal flash attention. Swapped QK^T (S^T = mfma(K,Q)) so the
// S^T D-layout chains directly into PV's B-operand with K=16 MFMAs (no
// transpose, no shuffles). Online softmax per query column (lane-local).
// grid = 512 (pairing swizzle: block i & i+256 get tiles j & 63-j -> balanced
// per-CU work), block = 128 (2 waves x 16 queries).
// ---------------------------------------------------------------------------
__global__ __launch_bounds__(128) void attn_kernel(const unsigned short* __restrict__ qw,
                                                   const unsigned short* __restrict__ kw,
                                                   const unsigned short* __restrict__ vw,
                                                   float* __restrict__ out) {
  int tid = threadIdx.x;
  int lane = tid & 63, w = tid >> 6;
  int ln = lane & 15, g = lane >> 4;
  int bid = blockIdx.x;
  int half = bid >> 8, idx = bid & 255;
  int b = idx >> 5, jj = idx & 31;
  int qtile = half ? (63 - jj) : jj;
  int t0 = qtile * 32;
  int tq0 = t0 + w * 16;
  int tq = tq0 + ln;   // this lane's query column

  // Q fragments (loop-invariant): B[k=h][n=t], 16B contiguous per lane
  const unsigned short* qp = qw + (size_t)(b * NT + tq) * NH + g * 8;
  bf16x8 qf0 = *(const bf16x8*)(qp);
  bf16x8 qf1 = *(const bf16x8*)(qp + 32);

  const unsigned short* kb = kw + (size_t)b * NT * NH + g * 8;
  const unsigned short* vb = vw + (size_t)b * NH * NT;

  f32x4 oacc[4];
#pragma unroll
  for (int i = 0; i < 4; ++i) oacc[i] = (f32x4){0.f, 0.f, 0.f, 0.f};
  float m = -1e30f, lsum = 0.f;

  int send = tq0 + 16;                 // exclusive key bound for this wave
  for (int s0 = 0; s0 < send; s0 += 64) {
    // ---- S^T = K_tile x Q^T : 4 subtiles of 16 keys, K(dim)=64 -> 2 mfma32
    f32x4 st4[4];
#pragma unroll
    for (int st = 0; st < 4; ++st) {
      const unsigned short* kp = kb + (size_t)(s0 + st * 16 + ln) * NH;
      bf16x8 k0 = *(const bf16x8*)(kp);
      bf16x8 k1 = *(const bf16x8*)(kp + 32);
      f32x4 a = (f32x4){0.f, 0.f, 0.f, 0.f};
      a = mfma32(k0, qf0, a);
      a = mfma32(k1, qf1, a);
      st4[st] = a;   // lane holds S^T[s=s0+st*16+g*4+r][t=tq], already *log2e*scale
    }
    // ---- causal mask (wave-uniform branch)
    if (s0 + 63 > tq0) {
#pragma unroll
      for (int st = 0; st < 4; ++st)
#pragma unroll
        for (int r = 0; r < 4; ++r)
          if (s0 + st * 16 + g * 4 + r > tq) st4[st][r] = -1e30f;
    }
    // ---- online softmax: row (=column t) max over 16 local + xor-16/32
    float tmax = -1e30f;
#pragma unroll
    for (int st = 0; st < 4; ++st)
#pragma unroll
      for (int r = 0; r < 4; ++r) tmax = fmaxf(tmax, st4[st][r]);
    tmax = fmaxf(tmax, __shfl_xor(tmax, 16));
    tmax = fmaxf(tmax, __shfl_xor(tmax, 32));
    float mnew = fmaxf(m, tmax);
    float sfac = exp2f(m - mnew);
    m = mnew;

    float psum = 0.f;
    bf16x4 pb[4];
#pragma unroll
    for (int st = 0; st < 4; ++st) {
#pragma unroll
      for (int r = 0; r < 4; ++r) {
        float p = exp2f(st4[st][r] - m);
        psum += p;
        pb[st][r] = (short)f2bf(p);   // D-layout == PV B-operand layout (K=16)
      }
    }
    psum += __shfl_xor(psum, 16);
    psum += __shfl_xor(psum, 32);
    lsum = lsum * sfac + psum;
#pragma unroll
    for (int hf = 0; hf < 4; ++hf)
#pragma unroll
      for (int r = 0; r < 4; ++r) oacc[hf][r] *= sfac;

    // ---- PV: out^T[h][t] += vT x P^T, 4 h-frags x 4 K=16 subtiles
#pragma unroll
    for (int hf = 0; hf < 4; ++hf) {
      const unsigned short* vp = vb + (size_t)(hf * 16 + ln) * NT + s0 + g * 4;
#pragma unroll
      for (int st = 0; st < 4; ++st) {
        bf16x4 va = *(const bf16x4*)(vp + st * 16);
        oacc[hf] = mfma16(va, pb[st], oacc[hf]);
      }
    }
  }

  // ---- epilogue: normalize, transpose out^T -> out[b][t][h] via LDS
  float inv = 1.f / lsum;
  __shared__ float olds[32][65];
#pragma unroll
  for (int hf = 0; hf < 4; ++hf)
#pragma unroll
    for (int r = 0; r < 4; ++r)
      olds[w * 16 + ln][hf * 16 + g * 4 + r] = oacc[hf][r] * inv;
  __syncthreads();
  int tl = tid >> 2, h0 = (tid & 3) * 16;
  size_t obase = (size_t)(b * NT + t0 + tl) * NH + h0;
#pragma unroll
  for (int vv = 0; vv < 4; ++vv) {
    float4 t4 = make_float4(olds[tl][h0 + vv * 4 + 0], olds[tl][h0 + vv * 4 + 1],
                            olds[tl][h0 + vv * 4 + 2], olds[tl][h0 + vv * 4 + 3]);
    *(float4*)(out + obase + vv * 4) = t4;
  }
}

// ---------------------------------------------------------------------------
extern "C" void kernel_launch(void* const* d_in, const int* in_sizes, int n_in,
                              void* d_out, int out_size, void* d_ws, size_t ws_size,
                              hipStream_t stream) {
  const float* x  = (const float*)d_in[0];
  const float* Wq = (const float*)d_in[1];
  const float* Wk = (const float*)d_in[2];
  const float* Wv = (const float*)d_in[3];
  float* out = (float*)d_out;

  // workspace layout (bf16): Wt[3][64][1024] | q[B*T][64] | k[B*T][64] | vT[B][64][T]
  unsigned short* Wt = (unsigned short*)d_ws;
  unsigned short* q  = (unsigned short*)((char*)d_ws + (1 << 19));  // 512 KB offset
  unsigned short* k  = q + (size_t)NB * NT * NH;
  unsigned short* v  = k + (size_t)NB * NT * NH;

  wt_kernel<<<48, 256, 0, stream>>>(Wq, Wk, Wv, Wt);
  proj_kernel<<<(NB * NT) / 64, 256, 0, stream>>>(x, Wt, q, k, v);
  attn_kernel<<<512, 128, 0, stream>>>(q, k, v, out);
}

// Round 2
// 89.404 us; speedup vs baseline: 1.8153x; 1.8153x over previous
//
#include <hip/hip_runtime.h>
#include <hip/hip_bf16.h>

#define NB 8
#define NT 2048
#define NC 1024
#define NH 64

typedef __attribute__((ext_vector_type(8))) short bf16x8;
typedef __attribute__((ext_vector_type(4))) short bf16x4;
typedef __attribute__((ext_vector_type(4))) float f32x4;

__device__ __forceinline__ unsigned short f2bf(float f) {
  __hip_bfloat16 h = __float2bfloat16(f);
  return __builtin_bit_cast(unsigned short, h);
}

__device__ __forceinline__ f32x4 mfma32(bf16x8 a, bf16x8 b, f32x4 c) {
  return __builtin_amdgcn_mfma_f32_16x16x32_bf16(a, b, c, 0, 0, 0);
}

#if __has_builtin(__builtin_amdgcn_mfma_f32_16x16x16bf16_1k)
__device__ __forceinline__ f32x4 mfma16(bf16x4 a, bf16x4 b, f32x4 c) {
  return __builtin_amdgcn_mfma_f32_16x16x16bf16_1k(a, b, c, 0, 0, 0);
}
#else
__device__ __forceinline__ f32x4 mfma16(bf16x4 a, bf16x4 b, f32x4 c) {
  asm volatile("v_mfma_f32_16x16x16_bf16 %0, %1, %2, %0\n\ts_nop 7"
               : "+v"(c) : "v"(a), "v"(b));
  return c;
}
#endif

// ---------------------------------------------------------------------------
// Kernel 0: weight transpose+convert. W[1024][64] f32 -> Wt[64][1024] bf16.
// Folds softmax scale * log2(e) into Wq so attention can use exp2 directly.
// ---------------------------------------------------------------------------
__global__ __launch_bounds__(256) void wt_kernel(const float* __restrict__ Wq,
                                                 const float* __restrict__ Wk,
                                                 const float* __restrict__ Wv,
                                                 unsigned short* __restrict__ Wt) {
  __shared__ float lds[64][65];
  int wi = blockIdx.x >> 4, kt = blockIdx.x & 15;
  const float* W = (wi == 0) ? Wq : ((wi == 1) ? Wk : Wv);
  float scale = (wi == 0) ? 0.18033688011112043f : 1.0f;  // 0.125 * log2(e)
  int tid = threadIdx.x;
#pragma unroll
  for (int i = 0; i < 16; ++i) {
    int idx = tid + i * 256;
    lds[idx >> 6][idx & 63] = W[(size_t)(kt * 64 + (idx >> 6)) * NH + (idx & 63)] * scale;
  }
  __syncthreads();
#pragma unroll
  for (int i = 0; i < 16; ++i) {
    int idx = tid + i * 256;
    int n = idx >> 6, kk = idx & 63;
    Wt[(size_t)(wi * 64 + n) * NC + kt * 64 + kk] = f2bf(lds[kk][n]);
  }
}

// ---------------------------------------------------------------------------
// Kernel 1: fused QKV projection, v2.
// 512 blocks x 256 thr. Block = 32 rows; x staged in LDS (bf16, XOR-swizzled)
// in two K=512 phases; 4 waves frag-split the 192 output cols (wave w owns
// n-cols [16w,16w+16) of each of q,k,v). Per iter: 2 ds_read_b128 +
// 3 global 16B weight loads + 6 MFMA. 2 waves/SIMD occupancy.
// ---------------------------------------------------------------------------
__global__ __launch_bounds__(256) void proj_kernel(const float* __restrict__ x,
                                                   const unsigned short* __restrict__ Wt,
                                                   unsigned short* __restrict__ qo,
                                                   unsigned short* __restrict__ ko,
                                                   unsigned short* __restrict__ vo) {
  __shared__ __align__(16) unsigned short xs[32 * 512];  // 32KB, swizzled
  __shared__ __align__(16) unsigned short vlds[64][40];

  int tid = threadIdx.x;
  int lane = tid & 63, w = tid >> 6;
  int ln = lane & 15, g = lane >> 4;
  int row0 = blockIdx.x * 32;

  const unsigned short* wpq = Wt + (size_t)(0 * 64 + w * 16 + ln) * NC;
  const unsigned short* wpk = Wt + (size_t)(1 * 64 + w * 16 + ln) * NC;
  const unsigned short* wpv = Wt + (size_t)(2 * 64 + w * 16 + ln) * NC;

  f32x4 acc[2][3];
#pragma unroll
  for (int rf = 0; rf < 2; ++rf)
#pragma unroll
    for (int j = 0; j < 3; ++j) acc[rf][j] = (f32x4){0.f, 0.f, 0.f, 0.f};

  for (int kk = 0; kk < 2; ++kk) {
    // ---- stage x[32][512] f32 -> bf16 LDS (swizzle: byte ^= (row&7)<<4)
    {
      int r2 = tid >> 7;            // 0..1
      int c4 = (tid & 127) * 4;     // 0..508
      const float* xp = x + (size_t)row0 * NC + kk * 512 + c4;
#pragma unroll
      for (int i = 0; i < 16; ++i) {
        int row = i * 2 + r2;
        float4 v4 = *(const float4*)(xp + (size_t)row * NC);
        bf16x4 b4;
        b4[0] = (short)f2bf(v4.x); b4[1] = (short)f2bf(v4.y);
        b4[2] = (short)f2bf(v4.z); b4[3] = (short)f2bf(v4.w);
        int byte = (row * 1024 + c4 * 2) ^ ((row & 7) << 4);
        *(bf16x4*)((char*)xs + byte) = b4;
      }
    }
    __syncthreads();
    // ---- MFMA over this K-phase
#pragma unroll 4
    for (int c0 = 0; c0 < 512; c0 += 32) {
      bf16x8 a[2];
#pragma unroll
      for (int rf = 0; rf < 2; ++rf) {
        int row = rf * 16 + ln;
        int byte = (row * 1024 + (c0 + g * 8) * 2) ^ ((row & 7) << 4);
        a[rf] = *(const bf16x8*)((char*)xs + byte);
      }
      int kg = kk * 512 + c0 + g * 8;
      bf16x8 bq = *(const bf16x8*)(wpq + kg);
      bf16x8 bk = *(const bf16x8*)(wpk + kg);
      bf16x8 bv = *(const bf16x8*)(wpv + kg);
#pragma unroll
      for (int rf = 0; rf < 2; ++rf) {
        acc[rf][0] = mfma32(a[rf], bq, acc[rf][0]);
        acc[rf][1] = mfma32(a[rf], bk, acc[rf][1]);
        acc[rf][2] = mfma32(a[rf], bv, acc[rf][2]);
      }
    }
    __syncthreads();
  }

  // ---- epilogue: q,k direct (2B stores, 32B segments); v via LDS transpose
#pragma unroll
  for (int rf = 0; rf < 2; ++rf)
#pragma unroll
    for (int r = 0; r < 4; ++r) {
      int row = row0 + rf * 16 + g * 4 + r;
      qo[(size_t)row * NH + w * 16 + ln] = f2bf(acc[rf][0][r]);
      ko[(size_t)row * NH + w * 16 + ln] = f2bf(acc[rf][1][r]);
      vlds[w * 16 + ln][rf * 16 + g * 4 + r] = f2bf(acc[rf][2][r]);
    }
  __syncthreads();
  int b = row0 / NT, t0b = row0 % NT;
  int hh = tid >> 2, ts = (tid & 3) * 8;
  *(bf16x8*)(vo + (size_t)(b * NH + hh) * NT + t0b + ts) = *(const bf16x8*)&vlds[hh][ts];
}

// ---------------------------------------------------------------------------
// Kernel 2: causal flash attention, v2. Swapped QK^T (S^T = mfma(K,Q)) chains
// into PV's B-operand with zero shuffles. NEW: 2-way key-split across wave
// pairs (wave ks handles 64-key chunks s0 % 128 == ks*64) with private online
// softmax state, merged in base-2 via LDS. 512 blocks x 256 thr -> 2 w/SIMD.
// ---------------------------------------------------------------------------
__global__ __launch_bounds__(256) void attn_kernel(const unsigned short* __restrict__ qw,
                                                   const unsigned short* __restrict__ kw,
                                                   const unsigned short* __restrict__ vw,
                                                   float* __restrict__ out) {
  int tid = threadIdx.x;
  int lane = tid & 63, w = tid >> 6;
  int qsub = w & 1, ks = w >> 1;
  int ln = lane & 15, g = lane >> 4;
  int bid = blockIdx.x;
  int half = bid >> 8, idx = bid & 255;
  int b = idx >> 5, jj = idx & 31;
  int qtile = half ? (63 - jj) : jj;   // pairing swizzle: balanced causal work
  int t0 = qtile * 32;
  int tq0 = t0 + qsub * 16;
  int tq = tq0 + ln;

  const unsigned short* qp = qw + (size_t)(b * NT + tq) * NH + g * 8;
  bf16x8 qf0 = *(const bf16x8*)(qp);
  bf16x8 qf1 = *(const bf16x8*)(qp + 32);

  const unsigned short* kb = kw + (size_t)b * NT * NH + g * 8;
  const unsigned short* vb = vw + (size_t)b * NH * NT;

  f32x4 oacc[4];
#pragma unroll
  for (int i = 0; i < 4; ++i) oacc[i] = (f32x4){0.f, 0.f, 0.f, 0.f};
  float m = -1e30f, lsum = 0.f;

  int send = tq0 + 16;                        // exclusive key bound
  for (int s0 = ks * 64; s0 < send; s0 += 128) {
    // ---- S^T = K_tile x Q^T
    f32x4 st4[4];
#pragma unroll
    for (int st = 0; st < 4; ++st) {
      const unsigned short* kp = kb + (size_t)(s0 + st * 16 + ln) * NH;
      bf16x8 k0 = *(const bf16x8*)(kp);
      bf16x8 k1 = *(const bf16x8*)(kp + 32);
      f32x4 a = (f32x4){0.f, 0.f, 0.f, 0.f};
      a = mfma32(k0, qf0, a);
      a = mfma32(k1, qf1, a);
      st4[st] = a;
    }
    // ---- causal mask (wave-uniform branch)
    if (s0 + 63 > tq0) {
#pragma unroll
      for (int st = 0; st < 4; ++st)
#pragma unroll
        for (int r = 0; r < 4; ++r)
          if (s0 + st * 16 + g * 4 + r > tq) st4[st][r] = -1e30f;
    }
    // ---- online softmax (base-2 logits)
    float tmax = -1e30f;
#pragma unroll
    for (int st = 0; st < 4; ++st)
#pragma unroll
      for (int r = 0; r < 4; ++r) tmax = fmaxf(tmax, st4[st][r]);
    tmax = fmaxf(tmax, __shfl_xor(tmax, 16));
    tmax = fmaxf(tmax, __shfl_xor(tmax, 32));
    float mnew = fmaxf(m, tmax);
    float sfac = exp2f(m - mnew);
    m = mnew;

    float psum = 0.f;
    bf16x4 pb[4];
#pragma unroll
    for (int st = 0; st < 4; ++st) {
#pragma unroll
      for (int r = 0; r < 4; ++r) {
        float p = exp2f(st4[st][r] - m);
        psum += p;
        pb[st][r] = (short)f2bf(p);
      }
    }
    psum += __shfl_xor(psum, 16);
    psum += __shfl_xor(psum, 32);
    lsum = lsum * sfac + psum;
#pragma unroll
    for (int hf = 0; hf < 4; ++hf)
#pragma unroll
      for (int r = 0; r < 4; ++r) oacc[hf][r] *= sfac;

    // ---- PV: out^T[h][t] += vT x P^T
#pragma unroll
    for (int hf = 0; hf < 4; ++hf) {
      const unsigned short* vp = vb + (size_t)(hf * 16 + ln) * NT + s0 + g * 4;
#pragma unroll
      for (int st = 0; st < 4; ++st) {
        bf16x4 va = *(const bf16x4*)(vp + st * 16);
        oacc[hf] = mfma16(va, pb[st], oacc[hf]);
      }
    }
  }

  // ---- merge the two key-split partials (base-2)
  __shared__ float mbuf[2][64][19];
  __shared__ float olds[32][65];
  if (ks == 1) {
    float* d = mbuf[qsub][lane];
    d[0] = m; d[1] = lsum;
#pragma unroll
    for (int hf = 0; hf < 4; ++hf)
#pragma unroll
      for (int r = 0; r < 4; ++r) d[2 + hf * 4 + r] = oacc[hf][r];
  }
  __syncthreads();
  if (ks == 0) {
    const float* d = mbuf[qsub][lane];
    float mB = d[0], lB = d[1];
    float mx = fmaxf(m, mB);
    float fA = exp2f(m - mx), fB = exp2f(mB - mx);
    float inv = 1.f / (lsum * fA + lB * fB);
#pragma unroll
    for (int hf = 0; hf < 4; ++hf)
#pragma unroll
      for (int r = 0; r < 4; ++r) {
        float o = oacc[hf][r] * fA + d[2 + hf * 4 + r] * fB;
        olds[qsub * 16 + ln][hf * 16 + g * 4 + r] = o * inv;
      }
  }
  __syncthreads();
  // ---- transposed store out[b][t][h]
  if (tid < 128) {
    int tl = tid >> 2, h0 = (tid & 3) * 16;
    size_t obase = (size_t)(b * NT + t0 + tl) * NH + h0;
#pragma unroll
    for (int vv = 0; vv < 4; ++vv) {
      float4 t4 = make_float4(olds[tl][h0 + vv * 4 + 0], olds[tl][h0 + vv * 4 + 1],
                              olds[tl][h0 + vv * 4 + 2], olds[tl][h0 + vv * 4 + 3]);
      *(float4*)(out + obase + vv * 4) = t4;
    }
  }
}

// ---------------------------------------------------------------------------
extern "C" void kernel_launch(void* const* d_in, const int* in_sizes, int n_in,
                              void* d_out, int out_size, void* d_ws, size_t ws_size,
                              hipStream_t stream) {
  const float* x  = (const float*)d_in[0];
  const float* Wq = (const float*)d_in[1];
  const float* Wk = (const float*)d_in[2];
  const float* Wv = (const float*)d_in[3];
  float* out = (float*)d_out;

  unsigned short* Wt = (unsigned short*)d_ws;
  unsigned short* q  = (unsigned short*)((char*)d_ws + (1 << 19));
  unsigned short* k  = q + (size_t)NB * NT * NH;
  unsigned short* v  = k + (size_t)NB * NT * NH;

  wt_kernel<<<48, 256, 0, stream>>>(Wq, Wk, Wv, Wt);
  proj_kernel<<<(NB * NT) / 32, 256, 0, stream>>>(x, Wt, q, k, v);
  attn_kernel<<<512, 256, 0, stream>>>(q, k, v, out);
}